// Round 3
// baseline (2610.965 us; speedup 1.0000x reference)
//
#include <hip/hip_runtime.h>
#include <math.h>

#define Bsz 128
#define Tsz 512
#define Hsz 1024
#define NM  8
#define MS  128
#define NT  512

// ---------------------------------------------------------------------------
// Transpose W_hh (1024x1024) into workspace: WT[j*H + i] = W[i*H + j]
// ---------------------------------------------------------------------------
__global__ __launch_bounds__(256)
void transpose_whh(const float* __restrict__ W, float* __restrict__ WT) {
    __shared__ float tile[32][33];
    const int bx = blockIdx.x * 32;
    const int by = blockIdx.y * 32;
    const int tx = threadIdx.x;
    const int ty = threadIdx.y;
    #pragma unroll
    for (int k = 0; k < 32; k += 8)
        tile[ty + k][tx] = W[(size_t)(by + ty + k) * Hsz + bx + tx];
    __syncthreads();
    #pragma unroll
    for (int k = 0; k < 32; k += 8)
        WT[(size_t)(bx + ty + k) * Hsz + by + tx] = tile[tx][ty + k];
}

__device__ __forceinline__ float dot8(const float4* w, const float4* h) {
    float a = 0.f;
    #pragma unroll
    for (int u = 0; u < 8; ++u)
        a += w[u].x * h[u].x + w[u].y * h[u].y + w[u].z * h[u].z + w[u].w * h[u].w;
    return a;
}

// ---------------------------------------------------------------------------
// Persistent per-batch-element Clockwork RNN kernel. grid=128, block=512.
//   row = tid&127 (output row in block), jc = tid>>7 (j-chunk of 32).
// Sp[p][jc*128+row]: jc-major partials -> lane-consecutive LDS (no conflicts).
// Weight blocks (r,c) for c<=2 live in registers (192 VGPRs/thread) —
// __launch_bounds__(512,2) raises the VGPR cap to 256 so they don't spill.
// ---------------------------------------------------------------------------
__global__ __launch_bounds__(NT, 2)
void cwrnn_kernel(const float* __restrict__ x,      // [B, T+1, 2, 1]
                  const float* __restrict__ W_ih,   // [H, 2]
                  const float* __restrict__ fc_w,   // [2, H]
                  const float* __restrict__ fc_b,   // [2]
                  const float* __restrict__ enc_w,  // [H, 2]
                  const float* __restrict__ WT,     // [H, H] transposed W_hh
                  float* __restrict__ out)          // [B, T, 2]
{
    __shared__ float h_s[Hsz];
    __shared__ float Sp[36][NT];          // [pair][jc*128+row], 73728 B
    __shared__ float x_s[(Tsz + 1) * 2];
    __shared__ float wih_s[Hsz * 2];
    __shared__ float fcw_s[2 * Hsz];
    __shared__ float out_s[Tsz * 2];
    __shared__ float ored[8 * 2];

    const int tid  = threadIdx.x;
    const int lane = tid & 63;
    const int wave = tid >> 6;
    const int row  = tid & (MS - 1);
    const int jc   = tid >> 7;            // 0..3
    const int b    = blockIdx.x;

    const float* xb = x + (size_t)b * (Tsz + 1) * 2;

    // ---- one-time preloads into LDS ----
    for (int i = tid; i < (Tsz + 1) * 2; i += NT) x_s[i] = xb[i];
    for (int i = tid; i < Hsz * 2; i += NT) wih_s[i] = W_ih[i];
    for (int i = tid; i < 2 * Hsz; i += NT) fcw_s[i] = fc_w[i];
    const float fb0 = fc_b[0], fb1 = fc_b[1];

    // ---- register weight cache: p=0:(0,0) 1:(0,1) 2:(1,1) 3:(0,2) 4:(1,2) 5:(2,2)
    float4 wr[6][8];
    {
        const int pr[6] = {0, 0, 1, 0, 1, 2};
        const int pc[6] = {0, 1, 1, 2, 2, 2};
        #pragma unroll
        for (int p = 0; p < 6; ++p) {
            const float* wp = WT + (size_t)(pc[p] * MS + jc * 32) * Hsz + pr[p] * MS + row;
            #pragma unroll
            for (int u = 0; u < 8; ++u) {
                wr[p][u].x = wp[(size_t)(4 * u + 0) * Hsz];
                wr[p][u].y = wp[(size_t)(4 * u + 1) * Hsz];
                wr[p][u].z = wp[(size_t)(4 * u + 2) * Hsz];
                wr[p][u].w = wp[(size_t)(4 * u + 3) * Hsz];
            }
        }
    }

    // ---- h0 = x[:,0] @ enc_w.T ----
    {
        const float x00 = xb[0], x01 = xb[1];
        for (int i = tid; i < Hsz; i += NT)
            h_s[i] = x00 * enc_w[i * 2] + x01 * enc_w[i * 2 + 1];
    }
    __syncthreads();

    const int sidx = jc * MS + row;       // lane-consecutive LDS index

    auto load_hcol = [&](int c, float4* hv) {
        const float4* hp = (const float4*)(h_s + c * MS + jc * 32);
        #pragma unroll
        for (int u = 0; u < 8; ++u) hv[u] = hp[u];   // wave-broadcast reads
    };

    // refresh all pairs in columns 0..A (module c just updated)
    auto refresh = [&](int A) {
        float4 hv[8];
        load_hcol(0, hv);
        Sp[0][sidx] = dot8(wr[0], hv);
        if (A >= 1) {
            load_hcol(1, hv);
            Sp[1][sidx] = dot8(wr[1], hv);
            Sp[2][sidx] = dot8(wr[2], hv);
        }
        if (A >= 2) {
            load_hcol(2, hv);
            Sp[3][sidx] = dot8(wr[3], hv);
            Sp[4][sidx] = dot8(wr[4], hv);
            Sp[5][sidx] = dot8(wr[5], hv);
        }
        if (A >= 3) {
            for (int c = 3; c <= A; ++c) {
                load_hcol(c, hv);
                const int pb = c * (c + 1) / 2;
                for (int r = 0; r <= c; ++r) {
                    const float* wp = WT + (size_t)(c * MS + jc * 32) * Hsz + r * MS + row;
                    float a = 0.f;
                    #pragma unroll
                    for (int u = 0; u < 8; ++u) {
                        a += wp[(size_t)(4 * u + 0) * Hsz] * hv[u].x;
                        a += wp[(size_t)(4 * u + 1) * Hsz] * hv[u].y;
                        a += wp[(size_t)(4 * u + 2) * Hsz] * hv[u].z;
                        a += wp[(size_t)(4 * u + 3) * Hsz] * hv[u].w;
                    }
                    Sp[pb + r][sidx] = a;
                }
            }
        }
    };

    refresh(7);                 // initial S from h0 (all 36 pairs)
    __syncthreads();

    for (int t = 0; t < Tsz; ++t) {
        const int A = (t == 0) ? 7 : min(__ffs(t) - 1, 7);
        const int nrows = (A + 1) * MS;
        const float xt0 = x_s[(t + 1) * 2];
        const float xt1 = x_s[(t + 1) * 2 + 1];

        // ---- P1: candidate + h update for active rows ----
        for (int g = tid; g < nrows; g += NT) {
            const int r = g >> 7, il = g & (MS - 1);
            float pre = xt0 * wih_s[g * 2] + xt1 * wih_s[g * 2 + 1];
            for (int c = r; c < NM; ++c) {
                const float* sp = Sp[c * (c + 1) / 2 + r];
                pre += (sp[il] + sp[MS + il]) + (sp[2 * MS + il] + sp[3 * MS + il]);
            }
            h_s[g] = tanhf(pre);
        }
        __syncthreads();

        // ---- P2: out[t] = h @ fc_w.T + fc_b (partials per wave) ----
        {
            const int j2 = tid * 2;
            float2 h2 = *(const float2*)&h_s[j2];
            float2 w0 = *(const float2*)&fcw_s[j2];
            float2 w1 = *(const float2*)&fcw_s[Hsz + j2];
            float a0 = h2.x * w0.x + h2.y * w0.y;
            float a1 = h2.x * w1.x + h2.y * w1.y;
            #pragma unroll
            for (int o = 32; o > 0; o >>= 1) {
                a0 += __shfl_down(a0, o, 64);
                a1 += __shfl_down(a1, o, 64);
            }
            if (lane == 0) { ored[wave * 2] = a0; ored[wave * 2 + 1] = a1; }
        }

        // ---- P3: eager refresh of columns whose module just updated ----
        refresh(A);
        __syncthreads();

        // ---- P4: stage the step's 2 outputs in LDS ----
        if (tid == 0) {
            float o0 = fb0, o1 = fb1;
            #pragma unroll
            for (int w = 0; w < 8; ++w) { o0 += ored[w * 2]; o1 += ored[w * 2 + 1]; }
            out_s[t * 2]     = o0;
            out_s[t * 2 + 1] = o1;
        }
        // ored WAR hazard: next write only after next step's barrier1,
        // which thread 0 must also reach. Safe.
    }

    __syncthreads();
    float* outb = out + (size_t)b * Tsz * 2;
    for (int i = tid; i < Tsz * 2; i += NT) outb[i] = out_s[i];
}

// ---------------------------------------------------------------------------
extern "C" void kernel_launch(void* const* d_in, const int* in_sizes, int n_in,
                              void* d_out, int out_size, void* d_ws, size_t ws_size,
                              hipStream_t stream) {
    const float* x     = (const float*)d_in[0];
    const float* W_ih  = (const float*)d_in[1];
    const float* W_hh  = (const float*)d_in[2];
    const float* fc_w  = (const float*)d_in[3];
    const float* fc_b  = (const float*)d_in[4];
    const float* enc_w = (const float*)d_in[5];
    float* outp = (float*)d_out;
    float* WT   = (float*)d_ws;            // 4 MB

    dim3 tb(32, 8);
    dim3 tg(Hsz / 32, Hsz / 32);
    transpose_whh<<<tg, tb, 0, stream>>>(W_hh, WT);

    cwrnn_kernel<<<Bsz, NT, 0, stream>>>(x, W_ih, fc_w, fc_b, enc_w, WT, outp);
}

// Round 4
// 1506.402 us; speedup vs baseline: 1.7332x; 1.7332x over previous
//
#include <hip/hip_runtime.h>
#include <math.h>

#define Bsz 128
#define Tsz 512
#define Hsz 1024
#define NM  8
#define MS  128
#define NT  512
#define NPAIR 36

// ---------------------------------------------------------------------------
// Retile W_hh into block-major WB.
//   pair p = tri index of (r,c), r<=c: p = c(c+1)/2 + r.
//   p==0 : WB[0][row*128 + j]  (j-fastest: feeds per-row register cache)
//   p>=1 : WB[p][j*128 + row]  (row-fastest: lane-coalesced float4-of-rows)
// ---------------------------------------------------------------------------
__global__ __launch_bounds__(256)
void retile_whh(const float* __restrict__ W, float* __restrict__ WB) {
    __shared__ float tile[MS][MS + 1];
    const int p = blockIdx.x;
    int c = 0;
    while ((c + 1) * (c + 2) / 2 <= p) ++c;
    const int r = p - c * (c + 1) / 2;
    const int t = threadIdx.x;
    if (p == 0) {
        for (int idx = t; idx < MS * MS; idx += 256) {
            const int row = idx >> 7, j = idx & (MS - 1);
            WB[idx] = W[row * Hsz + j];
        }
        return;
    }
    for (int idx = t; idx < MS * MS; idx += 256) {
        const int row = idx >> 7, j = idx & (MS - 1);
        tile[row][j] = W[(size_t)(r * MS + row) * Hsz + c * MS + j];  // coalesced read
    }
    __syncthreads();
    float* wb = WB + (size_t)p * MS * MS;
    for (int idx = t; idx < MS * MS; idx += 256) {
        const int j = idx >> 7, row = idx & (MS - 1);
        wb[idx] = tile[row][j];                                      // coalesced write
    }
}

__device__ __forceinline__ float fast_tanh(float x) {
    // 1 - 2/(e^{2x}+1); exp->inf gives 1, exp->0 gives -1. ~1e-6 abs err.
    const float e = __expf(2.0f * x);
    return 1.0f - 2.0f * __builtin_amdgcn_rcpf(e + 1.0f);
}

// ---------------------------------------------------------------------------
// Persistent per-batch-element Clockwork RNN. grid=128, block=512 (8 waves).
//
// Sp[p][jq*128+row]: 4 j-partials per (pair,row), summed for free in P1.
// (0,0) weights: registers (8 float4/thread, mapping row=tid&127, jc=tid>>7).
// pairs >=1: 4 pairs concurrently (slot=tid>>7); thread owns rows
//   row4..row4+3 and j-range jq*32..+31; 32 coalesced float4 loads from WB.
// ---------------------------------------------------------------------------
__global__ __launch_bounds__(NT)
void cwrnn_kernel(const float* __restrict__ x,      // [B, T+1, 2, 1]
                  const float* __restrict__ W_ih,   // [H, 2]
                  const float* __restrict__ fc_w,   // [2, H]
                  const float* __restrict__ fc_b,   // [2]
                  const float* __restrict__ enc_w,  // [H, 2]
                  const float* __restrict__ WB,     // retiled W_hh blocks
                  float* __restrict__ out)          // [B, T, 2]
{
    __shared__ float h_s[Hsz];
    __shared__ float Sp[NPAIR][NT];       // 73728 B
    __shared__ float x_s[(Tsz + 1) * 2];
    __shared__ float wih_s[Hsz * 2];
    __shared__ float fcw_s[2 * Hsz];
    __shared__ float out_s[Tsz * 2];
    __shared__ float ored[8 * 2];

    const int tid  = threadIdx.x;
    const int lane = tid & 63;
    const int wave = tid >> 6;
    const int b    = blockIdx.x;

    // mapping for (0,0) register path
    const int row = tid & (MS - 1);       // 0..127
    const int jc  = tid >> 7;             // 0..3
    // mapping for concurrent-pair path
    const int slot = tid >> 7;            // 0..3 (pair slot)
    const int s    = tid & 127;
    const int row4 = (s & 31) * 4;
    const int jq   = s >> 5;              // 0..3

    const float* xb = x + (size_t)b * (Tsz + 1) * 2;

    for (int i = tid; i < (Tsz + 1) * 2; i += NT) x_s[i] = xb[i];
    for (int i = tid; i < Hsz * 2; i += NT) wih_s[i] = W_ih[i];
    for (int i = tid; i < 2 * Hsz; i += NT) fcw_s[i] = fc_w[i];
    const float fb0 = fc_b[0], fb1 = fc_b[1];

    // ---- register cache of block (0,0): row's weights, j = jc*32..+31 ----
    float4 w00[8];
    {
        const float* wp = WB + row * MS + jc * 32;
        #pragma unroll
        for (int u = 0; u < 8; ++u) w00[u] = *(const float4*)(wp + 4 * u);
    }

    // ---- h0 = x[:,0] @ enc_w.T ----
    {
        const float x00 = xb[0], x01 = xb[1];
        for (int i = tid; i < Hsz; i += NT)
            h_s[i] = x00 * enc_w[i * 2] + x01 * enc_w[i * 2 + 1];
    }
    __syncthreads();

    // (0,0) refresh: every thread, scalar partial over its 32 j's
    auto refresh00 = [&]() {
        const float4* h4 = (const float4*)(h_s + jc * 32);
        float a = 0.f;
        #pragma unroll
        for (int u = 0; u < 8; ++u) {
            const float4 hv = h4[u];
            a += w00[u].x * hv.x + w00[u].y * hv.y + w00[u].z * hv.z + w00[u].w * hv.w;
        }
        Sp[0][jc * MS + row] = a;
    };

    // pairs >= 1: rounds of 4 concurrent pairs; P = total pairs this step
    auto refresh_hi = [&](int P) {
        for (int pb = 1; pb < P; pb += 4) {
            const int p = pb + slot;
            if (p < P) {
                const int c = (int)((sqrtf((float)(8 * p + 1)) - 1.0f) * 0.5f);
                const float* wb = WB + (size_t)p * MS * MS + jq * 32 * MS + row4;
                const float* hc = h_s + c * MS + jq * 32;
                float4 acc = {0.f, 0.f, 0.f, 0.f};
                #pragma unroll 8
                for (int j = 0; j < 32; ++j) {
                    const float4 wv = *(const float4*)(wb + j * MS);
                    const float hj = hc[j];
                    acc.x += wv.x * hj; acc.y += wv.y * hj;
                    acc.z += wv.z * hj; acc.w += wv.w * hj;
                }
                *(float4*)&Sp[p][jq * MS + row4] = acc;
            }
        }
    };

    refresh00();
    refresh_hi(NPAIR);
    __syncthreads();

    for (int t = 0; t < Tsz; ++t) {
        const int A = (t == 0) ? 7 : min(__ffs(t) - 1, 7);
        const int nrows = (A + 1) * MS;
        const float xt0 = x_s[(t + 1) * 2];
        const float xt1 = x_s[(t + 1) * 2 + 1];

        // ---- P1: candidate + h update for active rows ----
        for (int g = tid; g < nrows; g += NT) {
            const int r = g >> 7, il = g & (MS - 1);
            float pre = xt0 * wih_s[g * 2] + xt1 * wih_s[g * 2 + 1];
            for (int c = r; c < NM; ++c) {
                const float* sp = Sp[c * (c + 1) / 2 + r];
                pre += (sp[il] + sp[MS + il]) + (sp[2 * MS + il] + sp[3 * MS + il]);
            }
            h_s[g] = fast_tanh(pre);
        }
        __syncthreads();

        // ---- P3: eager refresh (issue VMEM early) ----
        refresh00();
        refresh_hi((A + 1) * (A + 2) / 2);

        // ---- P2: out[t] = h @ fc_w.T + fc_b (wave partials) ----
        {
            const int j2 = tid * 2;
            const float2 h2 = *(const float2*)&h_s[j2];
            const float2 w0 = *(const float2*)&fcw_s[j2];
            const float2 w1 = *(const float2*)&fcw_s[Hsz + j2];
            float a0 = h2.x * w0.x + h2.y * w0.y;
            float a1 = h2.x * w1.x + h2.y * w1.y;
            #pragma unroll
            for (int o = 32; o > 0; o >>= 1) {
                a0 += __shfl_down(a0, o, 64);
                a1 += __shfl_down(a1, o, 64);
            }
            if (lane == 0) { ored[wave * 2] = a0; ored[wave * 2 + 1] = a1; }
        }
        __syncthreads();

        // ---- P4: stage step outputs ----
        if (tid == 0) {
            float o0 = fb0, o1 = fb1;
            #pragma unroll
            for (int w = 0; w < 8; ++w) { o0 += ored[w * 2]; o1 += ored[w * 2 + 1]; }
            out_s[t * 2]     = o0;
            out_s[t * 2 + 1] = o1;
        }
        // ored WAR: rewritten only after next step's P1 barrier. Safe.
    }

    __syncthreads();
    float* outb = out + (size_t)b * Tsz * 2;
    for (int i = tid; i < Tsz * 2; i += NT) outb[i] = out_s[i];
}

// ---------------------------------------------------------------------------
extern "C" void kernel_launch(void* const* d_in, const int* in_sizes, int n_in,
                              void* d_out, int out_size, void* d_ws, size_t ws_size,
                              hipStream_t stream) {
    const float* x     = (const float*)d_in[0];
    const float* W_ih  = (const float*)d_in[1];
    const float* W_hh  = (const float*)d_in[2];
    const float* fc_w  = (const float*)d_in[3];
    const float* fc_b  = (const float*)d_in[4];
    const float* enc_w = (const float*)d_in[5];
    float* outp = (float*)d_out;
    float* WB   = (float*)d_ws;            // 36*16384*4 = 2.25 MB

    retile_whh<<<NPAIR, 256, 0, stream>>>(W_hh, WB);
    cwrnn_kernel<<<Bsz, NT, 0, stream>>>(x, W_ih, fc_w, fc_b, enc_w, WB, outp);
}